// Round 4
// baseline (3022.807 us; speedup 1.0000x reference)
//
#include <hip/hip_runtime.h>

// ---------------------------------------------------------------------------
// RecurrentActorCritic on MI355X.  B=128, T=256, F=128, H=256, 4H=1024, W=512, A=8.
// d_out (float): mean[1024] | log_std[8] | value[128] | c0n | h0n | c1n | h1n
// ---------------------------------------------------------------------------

typedef __attribute__((ext_vector_type(8))) short  frag8;   // 8 bf16 (4 VGPR)
typedef __attribute__((ext_vector_type(4))) float  f32x4;
typedef unsigned short u16;
typedef unsigned int   u32;

// workspace layout (bytes)
#define WS_FLAGS 0                               // 16KB counters (ctr0[256],ctr1[256])
#define WS_XT    16384                           // (T,B,F) bf16: 8.4MB
#define WS_W0B   (WS_XT + 128*256*128*2)         // Wi0 frag-layout bf16: 256KB
#define WS_W1B   (WS_W0B + 262144)               // Wi1 frag-layout bf16: 512KB
#define WS_YS0   (WS_W1B + 524288)               // (T,128,256) bf16: 16.8MB
#define WS_YS1   (WS_YS0 + 16777216)             // (T,128,256) bf16: 16.8MB
#define WS_H0M   (WS_YS1 + 16777216)             // (128,1024) bf16
#define WS_V1M   (WS_H0M + 262144)
#define WS_P     WS_XT                           // 16.8MB alias (xT/w*b/ys0 dead at head time)

__device__ __forceinline__ u16 f2b(float f) {
  u32 u = __builtin_bit_cast(u32, f);
  u32 r = (u + 0x7fffu + ((u >> 16) & 1u)) >> 16;   // RNE
  return (u16)r;
}
__device__ __forceinline__ float b2f(u16 b) {
  return __builtin_bit_cast(float, (u32)b << 16);
}
__device__ __forceinline__ float sigm(float x) { return 1.0f / (1.0f + __expf(-x)); }
__device__ __forceinline__ float tanh_(float x) {
  x = fminf(fmaxf(x, -15.0f), 15.0f);
  float e = __expf(2.0f * x);
  return (e - 1.0f) / (e + 1.0f);
}

// ---- system-scope (MALL) ops: bypass L1/L2, no cache-maintenance ----------
__device__ __forceinline__ frag8 coh16(const u16* p) {
  frag8 r;
  asm volatile("global_load_dwordx4 %0, %1, off sc0 sc1" : "=v"(r) : "v"(p) : "memory");
  return r;
}
__device__ __forceinline__ frag8 ld16c(const u16* p) {   // cached (L2) asm load
  frag8 r;
  asm volatile("global_load_dwordx4 %0, %1, off" : "=v"(r) : "v"(p) : "memory");
  return r;
}
__device__ __forceinline__ void coh_st32(u16* p, u32 v) {
  asm volatile("global_store_dword %0, %1, off sc0 sc1" :: "v"(p), "v"(v) : "memory");
}
__device__ __forceinline__ u32 coh_ld32(const u32* p) {
  u32 r;
  asm volatile("global_load_dword %0, %1, off sc0 sc1\n\t"
               "s_waitcnt vmcnt(0)" : "=v"(r) : "v"(p) : "memory");
  return r;
}
__device__ __forceinline__ void waitall() {
  asm volatile("s_waitcnt vmcnt(0)" ::: "memory");
  __builtin_amdgcn_sched_barrier(0);   // rule #18: pin MFMA below the wait
}

// producer: drain data stores, then one HW atomic at device coherence point
__device__ __forceinline__ void postcnt(u32* p) {
  asm volatile("s_waitcnt vmcnt(0)" ::: "memory");
  __syncthreads();
  if (threadIdx.x == 0)
    __hip_atomic_fetch_add(p, 1u, __ATOMIC_RELAXED, __HIP_MEMORY_SCOPE_AGENT);
}
// wave 0 polls per-lane (pointer, target); no sleep backoff
__device__ __forceinline__ void pollwait(const u32* p, u32 tgt) {
  if (threadIdx.x < 64) {
    while (true) {
      u32 v = coh_ld32(p);
      if (!__any(v < tgt)) break;
    }
  }
  __syncthreads();
}

// ---------------- K0: x (B,T,F) f32 -> xT (T,B,F) bf16 ---------------------
__global__ void convert_x_kernel(const float* __restrict__ x, u16* __restrict__ xT) {
  int g = blockIdx.x * 256 + threadIdx.x;
  int f4 = g & 31, rem = g >> 5;                   // rem = t*128 + b
  int t = rem >> 7, b = rem & 127;
  const float4 v = *reinterpret_cast<const float4*>(x + ((size_t)(b * 256 + t)) * 128 + f4 * 4);
  ushort4 ov;
  ov.x = f2b(v.x); ov.y = f2b(v.y); ov.z = f2b(v.z); ov.w = f2b(v.w);
  *reinterpret_cast<ushort4*>(xT + (size_t)rem * 128 + f4 * 4) = ov;
}

// ---------------- Wi -> bf16 MFMA-fragment-layout buffers ------------------
// frag index fi = ((blk*4 + tile)*NKX + kt)*64 + lane ; 8 bf16 each.
__global__ void wxb_kernel(const float* __restrict__ Wi0, const float* __restrict__ Wi1,
                           u16* __restrict__ w0b, u16* __restrict__ w1b) {
  int g = blockIdx.x * 256 + threadIdx.x;          // 49152 frags total
  const float* W; u16* dst; int NKX, fi;
  if (g < 16384) { W = Wi0; dst = w0b; NKX = 4; fi = g; }
  else           { W = Wi1; dst = w1b; NKX = 8; fi = g - 16384; }
  int l = fi & 63; int rest = fi >> 6;
  int kt = rest % NKX; rest /= NKX;
  int tile = rest & 3; int blk = rest >> 2;
  int gcol = tile * 256 + blk * 16 + (l & 15);
  int k0 = kt * 32 + (l >> 4) * 8;
#pragma unroll
  for (int j = 0; j < 8; ++j)
    dst[(size_t)fi * 8 + j] = f2b(W[(size_t)(k0 + j) * 1024 + gcol]);
}

// ---------------- fused persistent 2-layer LSTM ----------------------------
// 32 blocks: 0..15 = layer0 (hd slice 16 each), 16..31 = layer1 (1 step behind).
// ctr0[t] = #L0 blocks done with step t; ctr1[t] = #L1 blocks done with step t.
// L0 step t>0 : wait ctr0[t-1] == 16
// L1 step t   : wait ctr0[t] == 16  AND  (t>0: ctr1[t-1] == 16)
template <int NKX, bool XCOH, int LAYER>
__device__ __forceinline__ void lstm_body(
    const u16* __restrict__ xsrc, int xstride, const u16* __restrict__ wxb,
    const float* __restrict__ Wh, const float* __restrict__ bias,
    const float* __restrict__ cin, const float* __restrict__ hin,
    u16* __restrict__ ys, float* __restrict__ cOut, float* __restrict__ hOut,
    u32* __restrict__ ctr0, u32* __restrict__ ctr1, int blk) {
  const int tid = threadIdx.x, wv = tid >> 6, l = tid & 63;
  const int cl = l & 15, lk8 = (l >> 4) * 8;
  const int hdb = blk * 16, hd = hdb + cl;
  u32* ctrSelf = (LAYER == 0) ? ctr0 : ctr1;

  // resident Wh fragments (bf16, frag layout)
  frag8 wh[4][8];
#pragma unroll
  for (int g = 0; g < 4; ++g) {
    int gcol = g * 256 + hdb + cl;
#pragma unroll
    for (int kt = 0; kt < 8; ++kt) {
      frag8 f;
#pragma unroll
      for (int j = 0; j < 8; ++j)
        f[j] = (short)f2b(Wh[(size_t)(kt * 32 + lk8 + j) * 1024 + gcol]);
      wh[g][kt] = f;
    }
  }
  float bi[4];
#pragma unroll
  for (int g = 0; g < 4; ++g) bi[g] = bias[g * 256 + hdb + cl];
  float cst[2][4];
#pragma unroll
  for (int rt = 0; rt < 2; ++rt)
#pragma unroll
    for (int r = 0; r < 4; ++r)
      cst[rt][r] = cin[(wv * 32 + rt * 16 + (l >> 4) * 4 + r) * 256 + hd];

#pragma unroll 1
  for (int t = 0; t < 256; ++t) {
    frag8 xa[2][NKX], ha[2][8];

    if (LAYER == 0) {
      // x independent of recurrence: prefetch before the poll (cached path)
      const u16* xb = xsrc + (size_t)t * 128 * xstride;
#pragma unroll
      for (int rt = 0; rt < 2; ++rt) {
        int arow = wv * 32 + rt * 16 + cl;
#pragma unroll
        for (int kt = 0; kt < NKX; ++kt)
          xa[rt][kt] = ld16c(xb + (size_t)arow * xstride + kt * 32 + lk8);
      }
      if (t > 0) pollwait(ctr0 + (t - 1), 16u);   // poll drains prefetch too
    } else {
      // lane0: ctr0[t] ; lane1: ctr1[t-1] ; others duplicate lane0
      const u32* p = (l == 1 && t > 0) ? (ctr1 + (t - 1)) : (ctr0 + t);
      pollwait(p, 16u);
      const u16* xb = xsrc + (size_t)t * 128 * xstride;
#pragma unroll
      for (int rt = 0; rt < 2; ++rt) {
        int arow = wv * 32 + rt * 16 + cl;
#pragma unroll
        for (int kt = 0; kt < NKX; ++kt)
          xa[rt][kt] = coh16(xb + (size_t)arow * xstride + kt * 32 + lk8);
      }
    }

    if (t == 0) {
#pragma unroll
      for (int rt = 0; rt < 2; ++rt) {
        int arow = wv * 32 + rt * 16 + cl;
        const float* hp = hin + arow * 256;
#pragma unroll
        for (int kt = 0; kt < 8; ++kt) {
          const float* p = hp + kt * 32 + lk8;
          float4 q0 = *(const float4*)p, q1 = *(const float4*)(p + 4);
          frag8 f;
          f[0] = (short)f2b(q0.x); f[1] = (short)f2b(q0.y);
          f[2] = (short)f2b(q0.z); f[3] = (short)f2b(q0.w);
          f[4] = (short)f2b(q1.x); f[5] = (short)f2b(q1.y);
          f[6] = (short)f2b(q1.z); f[7] = (short)f2b(q1.w);
          ha[rt][kt] = f;
        }
      }
    } else {
      const u16* hb = ys + ((size_t)(t - 1) << 15);
#pragma unroll
      for (int rt = 0; rt < 2; ++rt) {
        int arow = wv * 32 + rt * 16 + cl;
#pragma unroll
        for (int kt = 0; kt < 8; ++kt)
          ha[rt][kt] = coh16(hb + arow * 256 + kt * 32 + lk8);
      }
    }

    f32x4 acc[4][2];
#pragma unroll
    for (int g = 0; g < 4; ++g)
#pragma unroll
      for (int rt = 0; rt < 2; ++rt)
        acc[g][rt] = f32x4{bi[g], bi[g], bi[g], bi[g]};

    if (LAYER == 0) {
      // x data already drained by the poll: x-MFMA overlaps h-load flight
#pragma unroll
      for (int kt = 0; kt < NKX; ++kt)
#pragma unroll
        for (int g = 0; g < 4; ++g) {
          frag8 wf = *(const frag8*)(wxb + ((((size_t)blk * 4 + g) * NKX + kt) * 64 + l) * 8);
          acc[g][0] = __builtin_amdgcn_mfma_f32_16x16x32_bf16(xa[0][kt], wf, acc[g][0], 0, 0, 0);
          acc[g][1] = __builtin_amdgcn_mfma_f32_16x16x32_bf16(xa[1][kt], wf, acc[g][1], 0, 0, 0);
        }
      waitall();
    } else {
      waitall();
#pragma unroll
      for (int kt = 0; kt < NKX; ++kt)
#pragma unroll
        for (int g = 0; g < 4; ++g) {
          frag8 wf = *(const frag8*)(wxb + ((((size_t)blk * 4 + g) * NKX + kt) * 64 + l) * 8);
          acc[g][0] = __builtin_amdgcn_mfma_f32_16x16x32_bf16(xa[0][kt], wf, acc[g][0], 0, 0, 0);
          acc[g][1] = __builtin_amdgcn_mfma_f32_16x16x32_bf16(xa[1][kt], wf, acc[g][1], 0, 0, 0);
        }
    }
#pragma unroll
    for (int kt = 0; kt < 8; ++kt)
#pragma unroll
      for (int g = 0; g < 4; ++g) {
        acc[g][0] = __builtin_amdgcn_mfma_f32_16x16x32_bf16(ha[0][kt], wh[g][kt], acc[g][0], 0, 0, 0);
        acc[g][1] = __builtin_amdgcn_mfma_f32_16x16x32_bf16(ha[1][kt], wh[g][kt], acc[g][1], 0, 0, 0);
      }

    // gate math + coherent h store (u32-packed via lane^1)
    u16* yd = ys + ((size_t)t << 15);
#pragma unroll
    for (int rt = 0; rt < 2; ++rt)
#pragma unroll
      for (int r = 0; r < 4; ++r) {
        int row = wv * 32 + rt * 16 + (l >> 4) * 4 + r;
        float zi = acc[0][rt][r], zf = acc[1][rt][r];
        float zg = acc[2][rt][r], zo = acc[3][rt][r];
        float cn = sigm(zf) * cst[rt][r] + sigm(zi) * tanh_(zg);
        float hn = sigm(zo) * tanh_(cn);
        cst[rt][r] = cn;
        u32 hb16 = (u32)f2b(hn);
        u32 pr = (u32)__shfl_xor((int)hb16, 1);
        if ((cl & 1) == 0)
          coh_st32(yd + row * 256 + hd, hb16 | (pr << 16));
        if (t == 255) {
          cOut[row * 256 + hd] = cn;
          hOut[row * 256 + hd] = hn;
        }
      }
    postcnt(ctrSelf + t);
  }
}

__launch_bounds__(256, 1)
__global__ void lstm_fused(const u16* __restrict__ xT,
                           const u16* __restrict__ w0b, const u16* __restrict__ w1b,
                           const float* __restrict__ Wh0, const float* __restrict__ b0,
                           const float* __restrict__ c0, const float* __restrict__ h0,
                           const float* __restrict__ Wh1, const float* __restrict__ b1,
                           const float* __restrict__ c1, const float* __restrict__ h1,
                           u16* __restrict__ ys0, u16* __restrict__ ys1,
                           float* __restrict__ out, u32* __restrict__ flags) {
  const int gid = blockIdx.x;
  u32* ctr0 = flags;
  u32* ctr1 = flags + 256;
  if (gid < 16)
    lstm_body<4, false, 0>(xT, 128, w0b, Wh0, b0, c0, h0, ys0,
                           out + 1160, out + 33928, ctr0, ctr1, gid);
  else
    lstm_body<8, true, 1>(ys0, 256, w1b, Wh1, b1, c1, h1, ys1,
                          out + 66696, out + 99464, ctr0, ctr1, gid - 16);
}

// ---------------- heads (validated in rounds 1/3) --------------------------
__launch_bounds__(256, 2)
__global__ void head_gemm_kernel(const u16* __restrict__ flatT,
                                 const float* __restrict__ Wv0,
                                 const float* __restrict__ Wm0,
                                 float* __restrict__ P) {
  const int bx = blockIdx.x;
  const int nb = bx >> 5, kb = bx & 31;
  const float* W = (nb >> 3) ? Wm0 : Wv0;
  const int ncb = (nb & 7) * 64;
  const int tid = threadIdx.x;
  const int wv = tid >> 6, l = tid & 63;
  const int lrow = l & 15, lk = (l >> 4) * 8;
  f32x4 acc[2][4] = {};
  const int kbase = kb * 2048;
#pragma unroll 2
  for (int ks = 0; ks < 64; ++ks) {
    int k0 = kbase + ks * 32;
    int t = k0 >> 8, h = k0 & 255;
    frag8 a[2];
#pragma unroll
    for (int mi = 0; mi < 2; ++mi) {
      int row = (2 * wv + mi) * 16 + lrow;
      a[mi] = *reinterpret_cast<const frag8*>(flatT + ((size_t)t * 128 + row) * 256 + h + lk);
    }
#pragma unroll
    for (int nt = 0; nt < 4; ++nt) {
      int col = ncb + nt * 16 + lrow;
      const float* wp = W + (size_t)(k0 + lk) * 512 + col;
      frag8 bfrag;
#pragma unroll
      for (int j = 0; j < 8; ++j) bfrag[j] = (short)f2b(wp[(size_t)j * 512]);
      acc[0][nt] = __builtin_amdgcn_mfma_f32_16x16x32_bf16(a[0], bfrag, acc[0][nt], 0, 0, 0);
      acc[1][nt] = __builtin_amdgcn_mfma_f32_16x16x32_bf16(a[1], bfrag, acc[1][nt], 0, 0, 0);
    }
  }
  float* Pb = P + (size_t)bx * 8192;
#pragma unroll
  for (int mi = 0; mi < 2; ++mi)
#pragma unroll
    for (int nt = 0; nt < 4; ++nt)
#pragma unroll
      for (int r = 0; r < 4; ++r) {
        int row = (2 * wv + mi) * 16 + (l >> 4) * 4 + r;
        int nl = nt * 16 + lrow;
        Pb[row * 64 + nl] = acc[mi][nt][r];
      }
}

__global__ void head_reduce_kernel(const float* __restrict__ P,
                                   const float* __restrict__ bv0,
                                   const float* __restrict__ bm0,
                                   u16* __restrict__ H0) {
  int o = blockIdx.x * 256 + threadIdx.x;
  int row = o >> 10, gcol = o & 1023;
  int nb = gcol >> 6, nl = gcol & 63;
  float s = 0.f;
#pragma unroll
  for (int kb = 0; kb < 32; ++kb)
    s += P[(size_t)(nb * 32 + kb) * 8192 + row * 64 + nl];
  s += (gcol < 512) ? bv0[gcol] : bm0[gcol - 512];
  H0[row * 1024 + gcol] = f2b(tanh_(s));
}

__launch_bounds__(256, 2)
__global__ void head_mid_kernel(const u16* __restrict__ H0,
                                const float* __restrict__ Wv1,
                                const float* __restrict__ Wm1,
                                const float* __restrict__ bv1,
                                const float* __restrict__ bm1,
                                u16* __restrict__ V1M) {
  const int nb = blockIdx.x;
  const int head = nb >> 3;
  const int ncb = (nb & 7) * 64;
  const float* W = head ? Wm1 : Wv1;
  const float* bsrc = head ? bm1 : bv1;
  const int tid = threadIdx.x, wv = tid >> 6, l = tid & 63;
  const int lrow = l & 15, lk = (l >> 4) * 8;
  const int aoff = head * 512;
  f32x4 acc[2][4] = {};
#pragma unroll 2
  for (int ks = 0; ks < 16; ++ks) {
    int k0 = ks * 32;
    frag8 a[2];
#pragma unroll
    for (int mi = 0; mi < 2; ++mi) {
      int row = (2 * wv + mi) * 16 + lrow;
      a[mi] = *reinterpret_cast<const frag8*>(H0 + row * 1024 + aoff + k0 + lk);
    }
#pragma unroll
    for (int nt = 0; nt < 4; ++nt) {
      int col = ncb + nt * 16 + lrow;
      const float* wp = W + (size_t)(k0 + lk) * 512 + col;
      frag8 bfrag;
#pragma unroll
      for (int j = 0; j < 8; ++j) bfrag[j] = (short)f2b(wp[(size_t)j * 512]);
      acc[0][nt] = __builtin_amdgcn_mfma_f32_16x16x32_bf16(a[0], bfrag, acc[0][nt], 0, 0, 0);
      acc[1][nt] = __builtin_amdgcn_mfma_f32_16x16x32_bf16(a[1], bfrag, acc[1][nt], 0, 0, 0);
    }
  }
#pragma unroll
  for (int mi = 0; mi < 2; ++mi)
#pragma unroll
    for (int nt = 0; nt < 4; ++nt)
#pragma unroll
      for (int r = 0; r < 4; ++r) {
        int row = (2 * wv + mi) * 16 + (l >> 4) * 4 + r;
        int cl = ncb + nt * 16 + lrow;
        float z = acc[mi][nt][r] + bsrc[cl];
        V1M[row * 1024 + head * 512 + cl] = f2b(tanh_(z));
      }
}

__global__ void head_final_kernel(const u16* __restrict__ V1M,
                                  const float* __restrict__ Wv2,
                                  const float* __restrict__ bv2,
                                  const float* __restrict__ Wm2,
                                  const float* __restrict__ bm2,
                                  const float* __restrict__ log_std,
                                  float* __restrict__ out) {
  int tid = threadIdx.x;   // 1024 threads
  {
    int row = tid >> 3, a = tid & 7;
    float s = 0.f;
    for (int k = 0; k < 512; ++k)
      s += b2f(V1M[row * 1024 + 512 + k]) * Wm2[k * 8 + a];
    out[row * 8 + a] = s + bm2[a];
  }
  if (tid < 128) {
    float s = 0.f;
    for (int k = 0; k < 512; ++k)
      s += b2f(V1M[tid * 1024 + k]) * Wv2[k];
    out[1032 + tid] = s + bv2[0];
  }
  if (tid < 8) out[1024 + tid] = log_std[tid];
}

// ---------------------------------------------------------------------------
extern "C" void kernel_launch(void* const* d_in, const int* in_sizes, int n_in,
                              void* d_out, int out_size, void* d_ws, size_t ws_size,
                              hipStream_t stream) {
  const float* x    = (const float*)d_in[0];
  const float* c0   = (const float*)d_in[1];
  const float* h0   = (const float*)d_in[2];
  const float* c1   = (const float*)d_in[3];
  const float* h1   = (const float*)d_in[4];
  const float* Wi0  = (const float*)d_in[5];
  const float* Wh0  = (const float*)d_in[6];
  const float* b0   = (const float*)d_in[7];
  const float* Wi1  = (const float*)d_in[8];
  const float* Wh1  = (const float*)d_in[9];
  const float* b1   = (const float*)d_in[10];
  const float* Wv0  = (const float*)d_in[11];
  const float* bv0  = (const float*)d_in[12];
  const float* Wv1  = (const float*)d_in[13];
  const float* bv1  = (const float*)d_in[14];
  const float* Wv2  = (const float*)d_in[15];
  const float* bv2  = (const float*)d_in[16];
  const float* Wm0  = (const float*)d_in[17];
  const float* bm0  = (const float*)d_in[18];
  const float* Wm1  = (const float*)d_in[19];
  const float* bm1  = (const float*)d_in[20];
  const float* Wm2  = (const float*)d_in[21];
  const float* bm2  = (const float*)d_in[22];
  const float* lstd = (const float*)d_in[23];
  float* out = (float*)d_out;
  char* ws = (char*)d_ws;

  u32* flags = (u32*)(ws + WS_FLAGS);
  u16* xT    = (u16*)(ws + WS_XT);
  u16* w0b   = (u16*)(ws + WS_W0B);
  u16* w1b   = (u16*)(ws + WS_W1B);
  u16* ys0   = (u16*)(ws + WS_YS0);
  u16* ys1   = (u16*)(ws + WS_YS1);
  float* P   = (float*)(ws + WS_P);
  u16* H0M   = (u16*)(ws + WS_H0M);
  u16* V1M   = (u16*)(ws + WS_V1M);

  hipMemsetAsync(ws + WS_FLAGS, 0, 16384, stream);
  convert_x_kernel<<<4096, 256, 0, stream>>>(x, xT);
  wxb_kernel<<<192, 256, 0, stream>>>(Wi0, Wi1, w0b, w1b);
  lstm_fused<<<32, 256, 0, stream>>>(xT, w0b, w1b, Wh0, b0, c0, h0,
                                     Wh1, b1, c1, h1, ys0, ys1, out, flags);
  head_gemm_kernel<<<512, 256, 0, stream>>>(ys1, Wv0, Wm0, P);
  head_reduce_kernel<<<512, 256, 0, stream>>>(P, bv0, bm0, H0M);
  head_mid_kernel<<<16, 256, 0, stream>>>(H0M, Wv1, Wm1, bv1, bm1, V1M);
  head_final_kernel<<<1, 1024, 0, stream>>>(V1M, Wv2, bv2, Wm2, bm2, lstd, out);
}

// Round 7
// 3015.284 us; speedup vs baseline: 1.0025x; 1.0025x over previous
//
#include <hip/hip_runtime.h>

// ---------------------------------------------------------------------------
// RecurrentActorCritic on MI355X.  B=128, T=256, F=128, H=256, 4H=1024, W=512, A=8.
// d_out (float): mean[1024] | log_std[8] | value[128] | c0n | h0n | c1n | h1n
// Round 7 = round 4 (PASSED) + single-lane counter polling with sleep pacing
// and 16B-strided counters (kill same-line MALL poll contention).
// ---------------------------------------------------------------------------

typedef __attribute__((ext_vector_type(8))) short  frag8;   // 8 bf16 (4 VGPR)
typedef __attribute__((ext_vector_type(4))) float  f32x4;
typedef unsigned short u16;
typedef unsigned int   u32;

// workspace layout (bytes)
#define WS_FLAGS 0                               // 16KB: ctr0[256]@0 (16B stride),
                                                 //        ctr1[256]@4096 (16B stride)
#define WS_XT    16384                           // (T,B,F) bf16: 8.4MB
#define WS_W0B   (WS_XT + 128*256*128*2)         // Wi0 frag-layout bf16: 256KB
#define WS_W1B   (WS_W0B + 262144)               // Wi1 frag-layout bf16: 512KB
#define WS_YS0   (WS_W1B + 524288)               // (T,128,256) bf16: 16.8MB
#define WS_YS1   (WS_YS0 + 16777216)             // (T,128,256) bf16: 16.8MB
#define WS_H0M   (WS_YS1 + 16777216)             // (128,1024) bf16
#define WS_V1M   (WS_H0M + 262144)
#define WS_P     WS_XT                           // 16.8MB alias (xT/w*b/ys0 dead at head time)

__device__ __forceinline__ u16 f2b(float f) {
  u32 u = __builtin_bit_cast(u32, f);
  u32 r = (u + 0x7fffu + ((u >> 16) & 1u)) >> 16;   // RNE
  return (u16)r;
}
__device__ __forceinline__ float b2f(u16 b) {
  return __builtin_bit_cast(float, (u32)b << 16);
}
__device__ __forceinline__ float sigm(float x) { return 1.0f / (1.0f + __expf(-x)); }
__device__ __forceinline__ float tanh_(float x) {
  x = fminf(fmaxf(x, -15.0f), 15.0f);
  float e = __expf(2.0f * x);
  return (e - 1.0f) / (e + 1.0f);
}

// ---- system-scope (MALL) ops: bypass L1/L2, no cache-maintenance ----------
__device__ __forceinline__ frag8 coh16(const u16* p) {
  frag8 r;
  asm volatile("global_load_dwordx4 %0, %1, off sc0 sc1" : "=v"(r) : "v"(p) : "memory");
  return r;
}
__device__ __forceinline__ frag8 ld16c(const u16* p) {   // cached (L2) asm load
  frag8 r;
  asm volatile("global_load_dwordx4 %0, %1, off" : "=v"(r) : "v"(p) : "memory");
  return r;
}
__device__ __forceinline__ void coh_st32(u16* p, u32 v) {
  asm volatile("global_store_dword %0, %1, off sc0 sc1" :: "v"(p), "v"(v) : "memory");
}
__device__ __forceinline__ u32 coh_ld32(const u32* p) {
  u32 r;
  asm volatile("global_load_dword %0, %1, off sc0 sc1\n\t"
               "s_waitcnt vmcnt(0)" : "=v"(r) : "v"(p) : "memory");
  return r;
}
__device__ __forceinline__ void waitall() {
  asm volatile("s_waitcnt vmcnt(0)" ::: "memory");
  __builtin_amdgcn_sched_barrier(0);   // rule #18: pin consumers below the wait
}

// producer: drain data stores, then one HW atomic at device coherence point
__device__ __forceinline__ void postcnt(u32* p) {
  asm volatile("s_waitcnt vmcnt(0)" ::: "memory");
  __syncthreads();
  if (threadIdx.x == 0)
    __hip_atomic_fetch_add(p, 1u, __ATOMIC_RELAXED, __HIP_MEMORY_SCOPE_AGENT);
}
// wave 0 polls; ONLY lanes with act=true load (1-2 loads/block/iter), others
// contribute tgt. s_sleep(1) paces the loop (~64cy) to cut MALL pressure.
__device__ __forceinline__ void pollwait(const u32* p, u32 tgt, bool act) {
  if (threadIdx.x < 64) {
    while (true) {
      u32 v = act ? coh_ld32(p) : tgt;
      if (!__any(v < tgt)) break;
      __builtin_amdgcn_s_sleep(1);
    }
  }
  __syncthreads();
}

// ---------------- K0: x (B,T,F) f32 -> xT (T,B,F) bf16 ---------------------
__global__ void convert_x_kernel(const float* __restrict__ x, u16* __restrict__ xT) {
  int g = blockIdx.x * 256 + threadIdx.x;
  int f4 = g & 31, rem = g >> 5;                   // rem = t*128 + b
  int t = rem >> 7, b = rem & 127;
  const float4 v = *reinterpret_cast<const float4*>(x + ((size_t)(b * 256 + t)) * 128 + f4 * 4);
  ushort4 ov;
  ov.x = f2b(v.x); ov.y = f2b(v.y); ov.z = f2b(v.z); ov.w = f2b(v.w);
  *reinterpret_cast<ushort4*>(xT + (size_t)rem * 128 + f4 * 4) = ov;
}

// ---------------- Wi -> bf16 MFMA-fragment-layout buffers ------------------
// frag index fi = ((blk*4 + tile)*NKX + kt)*64 + lane ; 8 bf16 each.
__global__ void wxb_kernel(const float* __restrict__ Wi0, const float* __restrict__ Wi1,
                           u16* __restrict__ w0b, u16* __restrict__ w1b) {
  int g = blockIdx.x * 256 + threadIdx.x;          // 49152 frags total
  const float* W; u16* dst; int NKX, fi;
  if (g < 16384) { W = Wi0; dst = w0b; NKX = 4; fi = g; }
  else           { W = Wi1; dst = w1b; NKX = 8; fi = g - 16384; }
  int l = fi & 63; int rest = fi >> 6;
  int kt = rest % NKX; rest /= NKX;
  int tile = rest & 3; int blk = rest >> 2;
  int gcol = tile * 256 + blk * 16 + (l & 15);
  int k0 = kt * 32 + (l >> 4) * 8;
#pragma unroll
  for (int j = 0; j < 8; ++j)
    dst[(size_t)fi * 8 + j] = f2b(W[(size_t)(k0 + j) * 1024 + gcol]);
}

// ---------------- fused persistent 2-layer LSTM ----------------------------
// 32 blocks: 0..15 = layer0 (hd slice 16 each), 16..31 = layer1 (1 step behind).
// ctr0[t] = #L0 blocks done with step t; ctr1[t] = #L1 blocks done with step t.
// L0 step t>0 : wait ctr0[t-1] == 16
// L1 step t   : wait ctr0[t] == 16  AND  (t>0: ctr1[t-1] == 16)
template <int NKX, int LAYER>
__device__ __forceinline__ void lstm_body(
    const u16* __restrict__ xsrc, int xstride, const u16* __restrict__ wxb,
    const float* __restrict__ Wh, const float* __restrict__ bias,
    const float* __restrict__ cin, const float* __restrict__ hin,
    u16* __restrict__ ys, float* __restrict__ cOut, float* __restrict__ hOut,
    u32* __restrict__ ctr0, u32* __restrict__ ctr1, int blk) {
  const int tid = threadIdx.x, wv = tid >> 6, l = tid & 63;
  const int cl = l & 15, lk8 = (l >> 4) * 8;
  const int hdb = blk * 16, hd = hdb + cl;
  u32* ctrSelf = (LAYER == 0) ? ctr0 : ctr1;

  // resident Wh fragments (bf16, frag layout)
  frag8 wh[4][8];
#pragma unroll
  for (int g = 0; g < 4; ++g) {
    int gcol = g * 256 + hdb + cl;
#pragma unroll
    for (int kt = 0; kt < 8; ++kt) {
      frag8 f;
#pragma unroll
      for (int j = 0; j < 8; ++j)
        f[j] = (short)f2b(Wh[(size_t)(kt * 32 + lk8 + j) * 1024 + gcol]);
      wh[g][kt] = f;
    }
  }
  float bi[4];
#pragma unroll
  for (int g = 0; g < 4; ++g) bi[g] = bias[g * 256 + hdb + cl];
  float cst[2][4];
#pragma unroll
  for (int rt = 0; rt < 2; ++rt)
#pragma unroll
    for (int r = 0; r < 4; ++r)
      cst[rt][r] = cin[(wv * 32 + rt * 16 + (l >> 4) * 4 + r) * 256 + hd];

#pragma unroll 1
  for (int t = 0; t < 256; ++t) {
    frag8 xa[2][NKX], ha[2][8];

    if (LAYER == 0) {
      // x independent of recurrence: prefetch before the poll (cached path)
      const u16* xb = xsrc + (size_t)t * 128 * xstride;
#pragma unroll
      for (int rt = 0; rt < 2; ++rt) {
        int arow = wv * 32 + rt * 16 + cl;
#pragma unroll
        for (int kt = 0; kt < NKX; ++kt)
          xa[rt][kt] = ld16c(xb + (size_t)arow * xstride + kt * 32 + lk8);
      }
      if (t > 0)                                     // poll drains prefetch too
        pollwait(ctr0 + (t - 1) * 4, 16u, l == 0);
    } else {
      // lane0 loads ctr0[t]; lane1 loads ctr1[t-1] (t>0); others no load
      const u32* p = (l == 1 && t > 0) ? (ctr1 + (t - 1) * 4) : (ctr0 + t * 4);
      bool act = (l == 0) || (l == 1 && t > 0);
      pollwait(p, 16u, act);
      const u16* xb = xsrc + (size_t)t * 128 * xstride;
#pragma unroll
      for (int rt = 0; rt < 2; ++rt) {
        int arow = wv * 32 + rt * 16 + cl;
#pragma unroll
        for (int kt = 0; kt < NKX; ++kt)
          xa[rt][kt] = coh16(xb + (size_t)arow * xstride + kt * 32 + lk8);
      }
    }

    if (t == 0) {
#pragma unroll
      for (int rt = 0; rt < 2; ++rt) {
        int arow = wv * 32 + rt * 16 + cl;
        const float* hp = hin + arow * 256;
#pragma unroll
        for (int kt = 0; kt < 8; ++kt) {
          const float* p = hp + kt * 32 + lk8;
          float4 q0 = *(const float4*)p, q1 = *(const float4*)(p + 4);
          frag8 f;
          f[0] = (short)f2b(q0.x); f[1] = (short)f2b(q0.y);
          f[2] = (short)f2b(q0.z); f[3] = (short)f2b(q0.w);
          f[4] = (short)f2b(q1.x); f[5] = (short)f2b(q1.y);
          f[6] = (short)f2b(q1.z); f[7] = (short)f2b(q1.w);
          ha[rt][kt] = f;
        }
      }
    } else {
      const u16* hb = ys + ((size_t)(t - 1) << 15);
#pragma unroll
      for (int rt = 0; rt < 2; ++rt) {
        int arow = wv * 32 + rt * 16 + cl;
#pragma unroll
        for (int kt = 0; kt < 8; ++kt)
          ha[rt][kt] = coh16(hb + arow * 256 + kt * 32 + lk8);
      }
    }

    f32x4 acc[4][2];
#pragma unroll
    for (int g = 0; g < 4; ++g)
#pragma unroll
      for (int rt = 0; rt < 2; ++rt)
        acc[g][rt] = f32x4{bi[g], bi[g], bi[g], bi[g]};

    if (LAYER == 0) {
      // x data already drained by the poll: x-MFMA overlaps h-load flight
#pragma unroll
      for (int kt = 0; kt < NKX; ++kt)
#pragma unroll
        for (int g = 0; g < 4; ++g) {
          frag8 wf = *(const frag8*)(wxb + ((((size_t)blk * 4 + g) * NKX + kt) * 64 + l) * 8);
          acc[g][0] = __builtin_amdgcn_mfma_f32_16x16x32_bf16(xa[0][kt], wf, acc[g][0], 0, 0, 0);
          acc[g][1] = __builtin_amdgcn_mfma_f32_16x16x32_bf16(xa[1][kt], wf, acc[g][1], 0, 0, 0);
        }
      waitall();
    } else {
      waitall();
#pragma unroll
      for (int kt = 0; kt < NKX; ++kt)
#pragma unroll
        for (int g = 0; g < 4; ++g) {
          frag8 wf = *(const frag8*)(wxb + ((((size_t)blk * 4 + g) * NKX + kt) * 64 + l) * 8);
          acc[g][0] = __builtin_amdgcn_mfma_f32_16x16x32_bf16(xa[0][kt], wf, acc[g][0], 0, 0, 0);
          acc[g][1] = __builtin_amdgcn_mfma_f32_16x16x32_bf16(xa[1][kt], wf, acc[g][1], 0, 0, 0);
        }
    }
#pragma unroll
    for (int kt = 0; kt < 8; ++kt)
#pragma unroll
      for (int g = 0; g < 4; ++g) {
        acc[g][0] = __builtin_amdgcn_mfma_f32_16x16x32_bf16(ha[0][kt], wh[g][kt], acc[g][0], 0, 0, 0);
        acc[g][1] = __builtin_amdgcn_mfma_f32_16x16x32_bf16(ha[1][kt], wh[g][kt], acc[g][1], 0, 0, 0);
      }

    // gate math + coherent h store (u32-packed via lane^1)
    u16* yd = ys + ((size_t)t << 15);
#pragma unroll
    for (int rt = 0; rt < 2; ++rt)
#pragma unroll
      for (int r = 0; r < 4; ++r) {
        int row = wv * 32 + rt * 16 + (l >> 4) * 4 + r;
        float zi = acc[0][rt][r], zf = acc[1][rt][r];
        float zg = acc[2][rt][r], zo = acc[3][rt][r];
        float cn = sigm(zf) * cst[rt][r] + sigm(zi) * tanh_(zg);
        float hn = sigm(zo) * tanh_(cn);
        cst[rt][r] = cn;
        u32 hb16 = (u32)f2b(hn);
        u32 pr = (u32)__shfl_xor((int)hb16, 1);
        if ((cl & 1) == 0)
          coh_st32(yd + row * 256 + hd, hb16 | (pr << 16));
        if (t == 255) {
          cOut[row * 256 + hd] = cn;
          hOut[row * 256 + hd] = hn;
        }
      }
    postcnt(ctrSelf + t * 4);
  }
}

__launch_bounds__(256, 1)
__global__ void lstm_fused(const u16* __restrict__ xT,
                           const u16* __restrict__ w0b, const u16* __restrict__ w1b,
                           const float* __restrict__ Wh0, const float* __restrict__ b0,
                           const float* __restrict__ c0, const float* __restrict__ h0,
                           const float* __restrict__ Wh1, const float* __restrict__ b1,
                           const float* __restrict__ c1, const float* __restrict__ h1,
                           u16* __restrict__ ys0, u16* __restrict__ ys1,
                           float* __restrict__ out, u32* __restrict__ flags) {
  const int gid = blockIdx.x;
  u32* ctr0 = flags;           // 16B stride
  u32* ctr1 = flags + 1024;    // byte 4096, 16B stride
  if (gid < 16)
    lstm_body<4, 0>(xT, 128, w0b, Wh0, b0, c0, h0, ys0,
                    out + 1160, out + 33928, ctr0, ctr1, gid);
  else
    lstm_body<8, 1>(ys0, 256, w1b, Wh1, b1, c1, h1, ys1,
                    out + 66696, out + 99464, ctr0, ctr1, gid - 16);
}

// ---------------- heads (validated in rounds 1/3/4) ------------------------
__launch_bounds__(256, 2)
__global__ void head_gemm_kernel(const u16* __restrict__ flatT,
                                 const float* __restrict__ Wv0,
                                 const float* __restrict__ Wm0,
                                 float* __restrict__ P) {
  const int bx = blockIdx.x;
  const int nb = bx >> 5, kb = bx & 31;
  const float* W = (nb >> 3) ? Wm0 : Wv0;
  const int ncb = (nb & 7) * 64;
  const int tid = threadIdx.x;
  const int wv = tid >> 6, l = tid & 63;
  const int lrow = l & 15, lk = (l >> 4) * 8;
  f32x4 acc[2][4] = {};
  const int kbase = kb * 2048;
#pragma unroll 2
  for (int ks = 0; ks < 64; ++ks) {
    int k0 = kbase + ks * 32;
    int t = k0 >> 8, h = k0 & 255;
    frag8 a[2];
#pragma unroll
    for (int mi = 0; mi < 2; ++mi) {
      int row = (2 * wv + mi) * 16 + lrow;
      a[mi] = *reinterpret_cast<const frag8*>(flatT + ((size_t)t * 128 + row) * 256 + h + lk);
    }
#pragma unroll
    for (int nt = 0; nt < 4; ++nt) {
      int col = ncb + nt * 16 + lrow;
      const float* wp = W + (size_t)(k0 + lk) * 512 + col;
      frag8 bfrag;
#pragma unroll
      for (int j = 0; j < 8; ++j) bfrag[j] = (short)f2b(wp[(size_t)j * 512]);
      acc[0][nt] = __builtin_amdgcn_mfma_f32_16x16x32_bf16(a[0], bfrag, acc[0][nt], 0, 0, 0);
      acc[1][nt] = __builtin_amdgcn_mfma_f32_16x16x32_bf16(a[1], bfrag, acc[1][nt], 0, 0, 0);
    }
  }
  float* Pb = P + (size_t)bx * 8192;
#pragma unroll
  for (int mi = 0; mi < 2; ++mi)
#pragma unroll
    for (int nt = 0; nt < 4; ++nt)
#pragma unroll
      for (int r = 0; r < 4; ++r) {
        int row = (2 * wv + mi) * 16 + (l >> 4) * 4 + r;
        int nl = nt * 16 + lrow;
        Pb[row * 64 + nl] = acc[mi][nt][r];
      }
}

__global__ void head_reduce_kernel(const float* __restrict__ P,
                                   const float* __restrict__ bv0,
                                   const float* __restrict__ bm0,
                                   u16* __restrict__ H0) {
  int o = blockIdx.x * 256 + threadIdx.x;
  int row = o >> 10, gcol = o & 1023;
  int nb = gcol >> 6, nl = gcol & 63;
  float s = 0.f;
#pragma unroll
  for (int kb = 0; kb < 32; ++kb)
    s += P[(size_t)(nb * 32 + kb) * 8192 + row * 64 + nl];
  s += (gcol < 512) ? bv0[gcol] : bm0[gcol - 512];
  H0[row * 1024 + gcol] = f2b(tanh_(s));
}

__launch_bounds__(256, 2)
__global__ void head_mid_kernel(const u16* __restrict__ H0,
                                const float* __restrict__ Wv1,
                                const float* __restrict__ Wm1,
                                const float* __restrict__ bv1,
                                const float* __restrict__ bm1,
                                u16* __restrict__ V1M) {
  const int nb = blockIdx.x;
  const int head = nb >> 3;
  const int ncb = (nb & 7) * 64;
  const float* W = head ? Wm1 : Wv1;
  const float* bsrc = head ? bm1 : bv1;
  const int tid = threadIdx.x, wv = tid >> 6, l = tid & 63;
  const int lrow = l & 15, lk = (l >> 4) * 8;
  const int aoff = head * 512;
  f32x4 acc[2][4] = {};
#pragma unroll 2
  for (int ks = 0; ks < 16; ++ks) {
    int k0 = ks * 32;
    frag8 a[2];
#pragma unroll
    for (int mi = 0; mi < 2; ++mi) {
      int row = (2 * wv + mi) * 16 + lrow;
      a[mi] = *reinterpret_cast<const frag8*>(H0 + row * 1024 + aoff + k0 + lk);
    }
#pragma unroll
    for (int nt = 0; nt < 4; ++nt) {
      int col = ncb + nt * 16 + lrow;
      const float* wp = W + (size_t)(k0 + lk) * 512 + col;
      frag8 bfrag;
#pragma unroll
      for (int j = 0; j < 8; ++j) bfrag[j] = (short)f2b(wp[(size_t)j * 512]);
      acc[0][nt] = __builtin_amdgcn_mfma_f32_16x16x32_bf16(a[0], bfrag, acc[0][nt], 0, 0, 0);
      acc[1][nt] = __builtin_amdgcn_mfma_f32_16x16x32_bf16(a[1], bfrag, acc[1][nt], 0, 0, 0);
    }
  }
#pragma unroll
  for (int mi = 0; mi < 2; ++mi)
#pragma unroll
    for (int nt = 0; nt < 4; ++nt)
#pragma unroll
      for (int r = 0; r < 4; ++r) {
        int row = (2 * wv + mi) * 16 + (l >> 4) * 4 + r;
        int cl = ncb + nt * 16 + lrow;
        float z = acc[mi][nt][r] + bsrc[cl];
        V1M[row * 1024 + head * 512 + cl] = f2b(tanh_(z));
      }
}

__global__ void head_final_kernel(const u16* __restrict__ V1M,
                                  const float* __restrict__ Wv2,
                                  const float* __restrict__ bv2,
                                  const float* __restrict__ Wm2,
                                  const float* __restrict__ bm2,
                                  const float* __restrict__ log_std,
                                  float* __restrict__ out) {
  int tid = threadIdx.x;   // 1024 threads
  {
    int row = tid >> 3, a = tid & 7;
    float s = 0.f;
    for (int k = 0; k < 512; ++k)
      s += b2f(V1M[row * 1024 + 512 + k]) * Wm2[k * 8 + a];
    out[row * 8 + a] = s + bm2[a];
  }
  if (tid < 128) {
    float s = 0.f;
    for (int k = 0; k < 512; ++k)
      s += b2f(V1M[tid * 1024 + k]) * Wv2[k];
    out[1032 + tid] = s + bv2[0];
  }
  if (tid < 8) out[1024 + tid] = log_std[tid];
}

// ---------------------------------------------------------------------------
extern "C" void kernel_launch(void* const* d_in, const int* in_sizes, int n_in,
                              void* d_out, int out_size, void* d_ws, size_t ws_size,
                              hipStream_t stream) {
  const float* x    = (const float*)d_in[0];
  const float* c0   = (const float*)d_in[1];
  const float* h0   = (const float*)d_in[2];
  const float* c1   = (const float*)d_in[3];
  const float* h1   = (const float*)d_in[4];
  const float* Wi0  = (const float*)d_in[5];
  const float* Wh0  = (const float*)d_in[6];
  const float* b0   = (const float*)d_in[7];
  const float* Wi1  = (const float*)d_in[8];
  const float* Wh1  = (const float*)d_in[9];
  const float* b1   = (const float*)d_in[10];
  const float* Wv0  = (const float*)d_in[11];
  const float* bv0  = (const float*)d_in[12];
  const float* Wv1  = (const float*)d_in[13];
  const float* bv1  = (const float*)d_in[14];
  const float* Wv2  = (const float*)d_in[15];
  const float* bv2  = (const float*)d_in[16];
  const float* Wm0  = (const float*)d_in[17];
  const float* bm0  = (const float*)d_in[18];
  const float* Wm1  = (const float*)d_in[19];
  const float* bm1  = (const float*)d_in[20];
  const float* Wm2  = (const float*)d_in[21];
  const float* bm2  = (const float*)d_in[22];
  const float* lstd = (const float*)d_in[23];
  float* out = (float*)d_out;
  char* ws = (char*)d_ws;

  u32* flags = (u32*)(ws + WS_FLAGS);
  u16* xT    = (u16*)(ws + WS_XT);
  u16* w0b   = (u16*)(ws + WS_W0B);
  u16* w1b   = (u16*)(ws + WS_W1B);
  u16* ys0   = (u16*)(ws + WS_YS0);
  u16* ys1   = (u16*)(ws + WS_YS1);
  float* P   = (float*)(ws + WS_P);
  u16* H0M   = (u16*)(ws + WS_H0M);
  u16* V1M   = (u16*)(ws + WS_V1M);

  hipMemsetAsync(ws + WS_FLAGS, 0, 16384, stream);
  convert_x_kernel<<<4096, 256, 0, stream>>>(x, xT);
  wxb_kernel<<<192, 256, 0, stream>>>(Wi0, Wi1, w0b, w1b);
  lstm_fused<<<32, 256, 0, stream>>>(xT, w0b, w1b, Wh0, b0, c0, h0,
                                     Wh1, b1, c1, h1, ys0, ys1, out, flags);
  head_gemm_kernel<<<512, 256, 0, stream>>>(ys1, Wv0, Wm0, P);
  head_reduce_kernel<<<512, 256, 0, stream>>>(P, bv0, bm0, H0M);
  head_mid_kernel<<<16, 256, 0, stream>>>(H0M, Wv1, Wm1, bv1, bm1, V1M);
  head_final_kernel<<<1, 1024, 0, stream>>>(V1M, Wv2, bv2, Wm2, bm2, lstd, out);
}